// Round 1
// baseline (303.997 us; speedup 1.0000x reference)
//
#include <hip/hip_runtime.h>
#include <math.h>

#define IN_FEATURES 1024
#define OUT_FEATURES 512
#define N_PULSE 10
#define NCOL (IN_FEATURES + N_PULSE)   /* 1034 */
#define BATCH 32
#define SORT_N 2048                    /* pow2 pad for bitonic */
#define MIN_W_ARG -0.3678794411714423

// ---------------- Kernel A: transpose weight [O,N] -> wT [N,O] ----------------
__global__ void transpose_w(const float* __restrict__ w, float* __restrict__ wT) {
    int i = blockIdx.x * blockDim.x + threadIdx.x;
    if (i >= NCOL * OUT_FEATURES) return;
    int n = i / OUT_FEATURES;
    int o = i - n * OUT_FEATURES;
    wT[i] = w[o * NCOL + n];           // coalesced write, L2-cached strided read
}

// ------------- Kernel B: per-batch-row stable sort + z precompute -------------
// One block per batch row. Bitonic sort of 2048 padded (key,idx) pairs in LDS.
// Lexicographic (key, idx) compare == stable ascending argsort (jnp semantics).
__global__ __launch_bounds__(1024) void sort_kernel(
        const float* __restrict__ x, const float* __restrict__ pulse,
        int* __restrict__ order_s, float* __restrict__ t_s,
        double* __restrict__ zs, double* __restrict__ zts) {
    __shared__ float key[SORT_N];
    __shared__ int   val[SORT_N];
    const int b = blockIdx.x;
    const int tid = threadIdx.x;

    for (int e = tid; e < SORT_N; e += 1024) {
        float t;
        if (e < IN_FEATURES)      t = x[b * IN_FEATURES + e];
        else if (e < NCOL)        t = pulse[e - IN_FEATURES];
        else                      t = 3.4e38f;   // pad: sorts to end
        key[e] = t;
        val[e] = e;
    }

    for (int kk = 2; kk <= SORT_N; kk <<= 1) {
        for (int j = kk >> 1; j > 0; j >>= 1) {
            __syncthreads();
            for (int e = tid; e < SORT_N; e += 1024) {
                int p = e ^ j;
                if (p > e) {
                    float a = key[e], c = key[p];
                    int  va = val[e], vc = val[p];
                    bool up   = ((e & kk) == 0);
                    bool agtc = (a > c) || (a == c && va > vc);
                    if (up == agtc) {
                        key[e] = c; key[p] = a;
                        val[e] = vc; val[p] = va;
                    }
                }
            }
        }
    }
    __syncthreads();

    for (int e = tid; e < NCOL; e += 1024) {
        float t  = key[e];
        int  idx = val[e];
        order_s[b * NCOL + e] = idx;
        t_s[b * NCOL + e] = t;
        bool vin = t < 1000.0f;
        double z = vin ? exp((double)t) : 0.0;
        zs [b * NCOL + e] = z;
        zts[b * NCOL + e] = z * (double)t;
    }
}

// ------------------------- Lambert W0 on [-1/e, 0] ---------------------------
__device__ __forceinline__ double lambertw0(double xx) {
    const double e = 2.718281828459045;
    double w = (xx < -0.25) ? (-1.0 + sqrt(fmax(2.0 * (1.0 + e * xx), 0.0)))
                            : xx * (1.0 - xx);
    #pragma unroll 4
    for (int i = 0; i < 12; ++i) {
        double ew = exp(w);
        double f  = w * ew - xx;
        double denom = ew * (w + 1.0) - (w + 2.0) * f / (2.0 * (w + 1.0) + 1e-12);
        w = w - f / (denom + 1e-12);
    }
    return w;
}

// ----------- Kernel C: per-(b,o) causal scan, first valid crossing -----------
__global__ void solve_kernel(const float* __restrict__ wT,
                             const int* __restrict__ order_s,
                             const float* __restrict__ t_s,
                             const double* __restrict__ zs,
                             const double* __restrict__ zts,
                             float* __restrict__ out) {
    int gid = blockIdx.x * blockDim.x + threadIdx.x;
    if (gid >= BATCH * OUT_FEATURES) return;
    int b = gid / OUT_FEATURES;
    int o = gid - b * OUT_FEATURES;

    const int*    ord = order_s + b * NCOL;
    const float*  ts  = t_s     + b * NCOL;
    const double* z   = zs      + b * NCOL;
    const double* zt  = zts     + b * NCOL;

    double A = 0.0, Bv = 0.0;
    float result = 1000.0f;

    for (int k = 0; k < NCOL; ++k) {
        float tk = ts[k];                       // wave-uniform load
        if (!(tk < 1000.0f)) break;             // no more valid inputs
        double w = (double)wT[ord[k] * OUT_FEATURES + o];  // coalesced across lanes
        A  += w * z[k];
        Bv += w * zt[k];
        if (A > 1e-10) {
            double boa = Bv / A;
            double arg = -exp(fmin(boa, 80.0)) / A;
            if (arg >= MIN_W_ARG) {
                double argc = fmin(fmax(arg, MIN_W_ARG), 0.0);
                double wl = lambertw0(argc);
                double tc = boa - wl;
                float nt = (k + 1 < NCOL) ? ts[k + 1] : 1000.0f;
                if (tc >= (double)tk && tc <= (double)nt) {
                    result = (float)tc;
                    break;
                }
            }
        }
    }
    out[gid] = result;
}

// --------------------------------- launcher ----------------------------------
extern "C" void kernel_launch(void* const* d_in, const int* in_sizes, int n_in,
                              void* d_out, int out_size, void* d_ws, size_t ws_size,
                              hipStream_t stream) {
    const float* x      = (const float*)d_in[0];
    const float* weight = (const float*)d_in[1];
    const float* pulse  = (const float*)d_in[2];
    float* out = (float*)d_out;

    char* ws = (char*)d_ws;
    double* zs  = (double*)ws;                          // 32*1034*8
    double* zts = zs + BATCH * NCOL;                    // 32*1034*8
    float*  wT  = (float*)(zts + BATCH * NCOL);         // 1034*512*4
    float*  t_s = wT + NCOL * OUT_FEATURES;             // 32*1034*4
    int* order_s = (int*)(t_s + BATCH * NCOL);          // 32*1034*4
    // total ~2.9 MB of workspace

    hipLaunchKernelGGL(transpose_w,
                       dim3((NCOL * OUT_FEATURES + 255) / 256), dim3(256), 0, stream,
                       weight, wT);
    hipLaunchKernelGGL(sort_kernel,
                       dim3(BATCH), dim3(1024), 0, stream,
                       x, pulse, order_s, t_s, zs, zts);
    hipLaunchKernelGGL(solve_kernel,
                       dim3((BATCH * OUT_FEATURES + 255) / 256), dim3(256), 0, stream,
                       wT, order_s, t_s, zs, zts, out);
}

// Round 2
// 164.118 us; speedup vs baseline: 1.8523x; 1.8523x over previous
//
#include <hip/hip_runtime.h>
#include <math.h>

#define IN_FEATURES 1024
#define OUT_FEATURES 512
#define N_PULSE 10
#define NCOL (IN_FEATURES + N_PULSE)   /* 1034 */
#define BATCH 32
#define SORT_N 2048                    /* pow2 pad for bitonic */
#define MIN_W_ARG -0.3678794411714423

// ---------------- Kernel A: transpose weight [O,N] -> wT [N,O] ----------------
__global__ void transpose_w(const float* __restrict__ w, float* __restrict__ wT) {
    int i = blockIdx.x * blockDim.x + threadIdx.x;
    if (i >= NCOL * OUT_FEATURES) return;
    int n = i / OUT_FEATURES;
    int o = i - n * OUT_FEATURES;
    wT[i] = w[o * NCOL + n];           // coalesced write, L2-cached strided read
}

// ------------- Kernel B: per-batch-row stable sort + z precompute -------------
__global__ __launch_bounds__(1024) void sort_kernel(
        const float* __restrict__ x, const float* __restrict__ pulse,
        int* __restrict__ order_s, float* __restrict__ t_s,
        double* __restrict__ zs, double* __restrict__ zts) {
    __shared__ float key[SORT_N];
    __shared__ int   val[SORT_N];
    const int b = blockIdx.x;
    const int tid = threadIdx.x;

    for (int e = tid; e < SORT_N; e += 1024) {
        float t;
        if (e < IN_FEATURES)      t = x[b * IN_FEATURES + e];
        else if (e < NCOL)        t = pulse[e - IN_FEATURES];
        else                      t = 3.4e38f;   // pad: sorts to end
        key[e] = t;
        val[e] = e;
    }

    for (int kk = 2; kk <= SORT_N; kk <<= 1) {
        for (int j = kk >> 1; j > 0; j >>= 1) {
            __syncthreads();
            for (int e = tid; e < SORT_N; e += 1024) {
                int p = e ^ j;
                if (p > e) {
                    float a = key[e], c = key[p];
                    int  va = val[e], vc = val[p];
                    bool up   = ((e & kk) == 0);
                    bool agtc = (a > c) || (a == c && va > vc);
                    if (up == agtc) {
                        key[e] = c; key[p] = a;
                        val[e] = vc; val[p] = va;
                    }
                }
            }
        }
    }
    __syncthreads();

    for (int e = tid; e < NCOL; e += 1024) {
        float t  = key[e];
        int  idx = val[e];
        order_s[b * NCOL + e] = idx;
        t_s[b * NCOL + e] = t;
        bool vin = t < 1000.0f;
        double z = vin ? exp((double)t) : 0.0;
        zs [b * NCOL + e] = z;
        zts[b * NCOL + e] = z * (double)t;
    }
}

// ------------------------- Lambert W0 on [-1/e, 0] ---------------------------
__device__ __forceinline__ double lambertw0(double xx) {
    const double e = 2.718281828459045;
    double w = (xx < -0.25) ? (-1.0 + sqrt(fmax(2.0 * (1.0 + e * xx), 0.0)))
                            : xx * (1.0 - xx);
    #pragma unroll 4
    for (int i = 0; i < 12; ++i) {
        double ew = exp(w);
        double f  = w * ew - xx;
        double denom = ew * (w + 1.0) - (w + 2.0) * f / (2.0 * (w + 1.0) + 1e-12);
        w = w - f / (denom + 1e-12);
    }
    return w;
}

// ----------- Kernel C: per-(b,o) causal scan, first valid crossing -----------
// Cheap exp-free window filter: on every window [t_k, t_{k+1}] with t<1,
// t_peak = 1 + B/A >= 1 > t, so V is rising on the window and
// t_cand in window  <=>  V(t_k) <= 1 <= V(t_{k+1}), i.e.
// A*t_k - B <= z_k  &&  A*t_{k+1} - B >= z_{k+1}   (z = e^t precomputed).
// Lambert-W runs only at the firing k (exact reference conditions re-verified).
__global__ __launch_bounds__(256) void solve_kernel(
        const float* __restrict__ wT,
        const int* __restrict__ order_s,
        const float* __restrict__ t_s,
        const double* __restrict__ zs,
        const double* __restrict__ zts,
        float* __restrict__ out) {
    const int b = blockIdx.x >> 1;                       // block-uniform -> s_load tables
    const int o = ((blockIdx.x & 1) << 8) | threadIdx.x;

    const int*    __restrict__ ord = order_s + b * NCOL;
    const float*  __restrict__ ts  = t_s     + b * NCOL;
    const double* __restrict__ z   = zs      + b * NCOL;
    const double* __restrict__ zt  = zts     + b * NCOL;

    double A = 0.0, Bv = 0.0;
    float result = 1000.0f;

    for (int k = 0; k < NCOL; ++k) {
        float tk = ts[k];                                // uniform
        if (!(tk < 1000.0f)) break;                      // no more valid inputs
        double zk  = z[k];
        double ztk = zt[k];
        double w = (double)wT[ord[k] * OUT_FEATURES + o]; // coalesced 256B/wave
        A  = fma(w, zk,  A);
        Bv = fma(w, ztk, Bv);
        if (!(A > 1e-10)) continue;

        bool last = (k == NCOL - 1) || !(ts[k + 1] < 1000.0f);
        float tn = last ? 1000.0f : ts[k + 1];
        bool maybe;
        if (last) {
            maybe = true;                                // decide on exact path (once per lane max)
        } else {
            double zn = z[k + 1];
            maybe = (fma(A, (double)tk, -Bv) <= zk) &&
                    (fma(A, (double)tn, -Bv) >= zn);
        }
        if (maybe) {
            double boa = Bv / A;
            double arg = -exp(fmin(boa, 80.0)) / A;
            if (arg >= MIN_W_ARG) {
                double wl = lambertw0(fmin(fmax(arg, MIN_W_ARG), 0.0));
                double tc = boa - wl;
                if (tc >= (double)tk && tc <= (double)tn) {
                    result = (float)tc;
                    break;
                }
            }
        }
    }
    out[b * OUT_FEATURES + o] = result;
}

// --------------------------------- launcher ----------------------------------
extern "C" void kernel_launch(void* const* d_in, const int* in_sizes, int n_in,
                              void* d_out, int out_size, void* d_ws, size_t ws_size,
                              hipStream_t stream) {
    const float* x      = (const float*)d_in[0];
    const float* weight = (const float*)d_in[1];
    const float* pulse  = (const float*)d_in[2];
    float* out = (float*)d_out;

    char* ws = (char*)d_ws;
    double* zs  = (double*)ws;                          // 32*1034*8
    double* zts = zs + BATCH * NCOL;                    // 32*1034*8
    float*  wT  = (float*)(zts + BATCH * NCOL);         // 1034*512*4
    float*  t_s = wT + NCOL * OUT_FEATURES;             // 32*1034*4
    int* order_s = (int*)(t_s + BATCH * NCOL);          // 32*1034*4

    hipLaunchKernelGGL(transpose_w,
                       dim3((NCOL * OUT_FEATURES + 255) / 256), dim3(256), 0, stream,
                       weight, wT);
    hipLaunchKernelGGL(sort_kernel,
                       dim3(BATCH), dim3(1024), 0, stream,
                       x, pulse, order_s, t_s, zs, zts);
    hipLaunchKernelGGL(solve_kernel,
                       dim3(BATCH * OUT_FEATURES / 256), dim3(256), 0, stream,
                       wT, order_s, t_s, zs, zts, out);
}